// Round 4
// baseline (24413.269 us; speedup 1.0000x reference)
//
#include <hip/hip_runtime.h>
#include <cstddef>

// SafetyReflexSNN: 5-layer LIF SNN, B=128, T=512.
//
// ROUND 15: same 6-stage phase pipeline + 3.93 MB byte-spike workspace as
// round 14 (proven), rebuilt GEMM:
//  - 32x64 tiles, micro-tile 4x4 (2 x ds_read_b128 -> 16 FMA): 4x fewer
//    LDS ops per FMA than round 14 (the latency-bound 2xds_read_b64:4FMA).
//  - K=1024 stages (L1, 2a, 2b, L3): 256-thr blocks, wave-group K-split at
//    the legal k=512 BLAS panel boundary (thr 0-127: k<512, 128-255:
//    k>=512), folded in LDS as __fadd_rn(panL, panH) == the round-14 chain
//    fadd(fadd(0,panL),panH) (0+x exact; zero-sign diffs are value-equal
//    and never escape). Halves per-wave serial work, ~doubles wave count.
//  - K=512 stages (L0, L4): whole-K 256-thr blocks, micro 4x2.
//  - A staged TRANSPOSED [k][b] as floats (byte->float cvt at staging);
//    W staged TRANSPOSED [k][o] (pad 68 keeps rows 16B-aligned).
//  - 2-deep register prefetch + LDS double-buffer, ONE barrier per k-tile.
//
// NUMERICS (absmax 0.0 inherited): per output element the op sequence is
// value-identical to round-11/14: ascending-k fmaf chain per panel; K=1024
// combines panels with one __fadd_rn(low, high); layer-2 combine = one
// __fadd_rn(W2a_res, W2b_res); LIF = __fmul_rn / __fadd_rn / __fsub_rn;
// counts accumulated in ascending t.

#define NB 128
#define NT 512

// ---- workspace layout (floats) ----
enum : size_t {
  OFF_V0   = 0,                       // [128][1024]
  OFF_V1   = OFF_V0 + 131072,
  OFF_V2   = OFF_V1 + 131072,
  OFF_V3   = OFF_V2 + 131072,         // [128][512]
  OFF_VO   = OFF_V3 + 65536,          // [128][128]
  OFF_CNT  = OFF_VO + 16384,          // [128][128]
  OFF_C2A  = OFF_CNT + 16384,         // 2 x [128][1024] float
  OFF_BYTE = OFF_C2A + 262144,        // byte region starts here (float idx)
  WS_FLOATS = OFF_BYTE + 229376       // 983040 floats = 3.93 MB
};
#define BS0 0
#define BS1 262144
#define BS2 524288
#define BS3 786432

__global__ __launch_bounds__(256) void init_kernel(float* __restrict__ wf) {
  size_t i = (size_t)blockIdx.x * blockDim.x + threadIdx.x;
  size_t stride = (size_t)gridDim.x * blockDim.x;
  for (size_t j = i; j < WS_FLOATS; j += stride) wf[j] = 0.0f;
}

// ---- LDS staging helpers (transposed layouts) ----
__device__ __forceinline__ void wrA8(float (&A)[32][32], int ac, int ar, uint2 u) {
  A[ac + 0][ar] = (float)(u.x & 0xff);
  A[ac + 1][ar] = (float)((u.x >> 8) & 0xff);
  A[ac + 2][ar] = (float)((u.x >> 16) & 0xff);
  A[ac + 3][ar] = (float)(u.x >> 24);
  A[ac + 4][ar] = (float)(u.y & 0xff);
  A[ac + 5][ar] = (float)((u.y >> 8) & 0xff);
  A[ac + 6][ar] = (float)((u.y >> 16) & 0xff);
  A[ac + 7][ar] = (float)(u.y >> 24);
}
__device__ __forceinline__ void wrW16(float (&Wt)[32][68], int wk, int wr,
    const float4& w0, const float4& w1, const float4& w2, const float4& w3) {
  Wt[wk + 0][wr]      = w0.x; Wt[wk + 1][wr]      = w0.y;
  Wt[wk + 2][wr]      = w0.z; Wt[wk + 3][wr]      = w0.w;
  Wt[wk + 0][wr + 16] = w1.x; Wt[wk + 1][wr + 16] = w1.y;
  Wt[wk + 2][wr + 16] = w1.z; Wt[wk + 3][wr + 16] = w1.w;
  Wt[wk + 0][wr + 32] = w2.x; Wt[wk + 1][wr + 32] = w2.y;
  Wt[wk + 2][wr + 32] = w2.z; Wt[wk + 3][wr + 32] = w2.w;
  Wt[wk + 0][wr + 48] = w3.x; Wt[wk + 1][wr + 48] = w3.y;
  Wt[wk + 2][wr + 48] = w3.z; Wt[wk + 3][wr + 48] = w3.w;
}
__device__ __forceinline__ void wrA4f(float (&A)[32][32], int ac4, int ar, float4 f) {
  A[ac4 + 0][ar] = f.x; A[ac4 + 1][ar] = f.y;
  A[ac4 + 2][ar] = f.z; A[ac4 + 3][ar] = f.w;
}
__device__ __forceinline__ void wrA4b(float (&A)[32][32], int ac4, int ar, unsigned u) {
  A[ac4 + 0][ar] = (float)(u & 0xff);
  A[ac4 + 1][ar] = (float)((u >> 8) & 0xff);
  A[ac4 + 2][ar] = (float)((u >> 16) & 0xff);
  A[ac4 + 3][ar] = (float)(u >> 24);
}
__device__ __forceinline__ void wrW8(float (&Wt)[32][68], int wk2, int wr,
    const float4& w0, const float4& w1) {
  Wt[wk2 + 0][wr] = w0.x; Wt[wk2 + 1][wr] = w0.y;
  Wt[wk2 + 2][wr] = w0.z; Wt[wk2 + 3][wr] = w0.w;
  Wt[wk2 + 4][wr] = w1.x; Wt[wk2 + 5][wr] = w1.y;
  Wt[wk2 + 6][wr] = w1.z; Wt[wk2 + 7][wr] = w1.w;
}

// ---- split GEMM: K=1024, 256 thr, wave-group panel split at k=512.
// Tile 32 (b) x 64 (o). Per group: micro 4x4, NKT=16 k-tiles of 32.
// A: byte spikes [b][1024]. Result (panL+panH folded) valid for grp 0.
__device__ __forceinline__ void gemm_split(
    const unsigned char* __restrict__ Abase, int Astride,
    const float* __restrict__ W,  // [o][1024]
    int bBase, int oBase,
    float (&As)[2][2][32][32], float (&Ws)[2][2][32][68],
    float (&pan)[4][4])
{
  const int tid = threadIdx.x;
  const int grp = tid >> 7, lt = tid & 127;
  const int ar = lt >> 2, ac = (lt & 3) << 3;   // A stage: row ar, 8 k-bytes
  const int wr = lt >> 3, wk = (lt & 7) << 2;   // W stage: rows wr+16r, 4 k
  const int tb4 = (lt >> 4) << 2;               // compute: 4 b-rows
  const int to4 = (lt & 15) << 2;               // compute: 4 o-cols
  const int kb = grp << 9;

  const unsigned char* Arow = Abase + (size_t)(bBase + ar) * Astride + kb + ac;
  const float* Wr = W + (size_t)(oBase + wr) * 1024 + kb + wk;

  // prologue: tile 0 -> LDS buf 0
  {
    uint2 a = *(const uint2*)(Arow);
    float4 w0 = *(const float4*)(Wr);
    float4 w1 = *(const float4*)(Wr + 16 * 1024);
    float4 w2 = *(const float4*)(Wr + 32 * 1024);
    float4 w3 = *(const float4*)(Wr + 48 * 1024);
    wrA8(As[grp][0], ac, ar, a);
    wrW16(Ws[grp][0], wk, wr, w0, w1, w2, w3);
  }
  // tile 1 -> regs
  uint2 pa = *(const uint2*)(Arow + 32);
  float4 pw0 = *(const float4*)(Wr + 32);
  float4 pw1 = *(const float4*)(Wr + 32 + 16 * 1024);
  float4 pw2 = *(const float4*)(Wr + 32 + 32 * 1024);
  float4 pw3 = *(const float4*)(Wr + 32 + 48 * 1024);
  __syncthreads();

  int cb = 0;
#pragma unroll 1
  for (int kt = 0; kt < 16; ++kt) {
    uint2 na; float4 nw0, nw1, nw2, nw3;
    if (kt + 2 < 16) {  // 2-deep prefetch
      const int ko = (kt + 2) << 5;
      na  = *(const uint2*)(Arow + ko);
      nw0 = *(const float4*)(Wr + ko);
      nw1 = *(const float4*)(Wr + ko + 16 * 1024);
      nw2 = *(const float4*)(Wr + ko + 32 * 1024);
      nw3 = *(const float4*)(Wr + ko + 48 * 1024);
    }
#pragma unroll
    for (int k = 0; k < 32; ++k) {
      const float4 a = *(const float4*)&As[grp][cb][k][tb4];
      const float4 w = *(const float4*)&Ws[grp][cb][k][to4];
      pan[0][0] = fmaf(a.x, w.x, pan[0][0]);
      pan[0][1] = fmaf(a.x, w.y, pan[0][1]);
      pan[0][2] = fmaf(a.x, w.z, pan[0][2]);
      pan[0][3] = fmaf(a.x, w.w, pan[0][3]);
      pan[1][0] = fmaf(a.y, w.x, pan[1][0]);
      pan[1][1] = fmaf(a.y, w.y, pan[1][1]);
      pan[1][2] = fmaf(a.y, w.z, pan[1][2]);
      pan[1][3] = fmaf(a.y, w.w, pan[1][3]);
      pan[2][0] = fmaf(a.z, w.x, pan[2][0]);
      pan[2][1] = fmaf(a.z, w.y, pan[2][1]);
      pan[2][2] = fmaf(a.z, w.z, pan[2][2]);
      pan[2][3] = fmaf(a.z, w.w, pan[2][3]);
      pan[3][0] = fmaf(a.w, w.x, pan[3][0]);
      pan[3][1] = fmaf(a.w, w.y, pan[3][1]);
      pan[3][2] = fmaf(a.w, w.z, pan[3][2]);
      pan[3][3] = fmaf(a.w, w.w, pan[3][3]);
    }
    if (kt + 1 < 16) {  // write tile kt+1 (read at kt-1 done by last barrier)
      const int nb = cb ^ 1;
      wrA8(As[grp][nb], ac, ar, pa);
      wrW16(Ws[grp][nb], wk, wr, pw0, pw1, pw2, pw3);
    }
    if (kt + 2 < 16) { pa = na; pw0 = nw0; pw1 = nw1; pw2 = nw2; pw3 = nw3; }
    __syncthreads();
    cb ^= 1;
  }

  // fold: high panel -> LDS (reuse group-1 A region, 8 KB), low adds it.
  float* foldp = &As[1][0][0][0];
  if (grp == 1) {
#pragma unroll
    for (int i = 0; i < 4; ++i) {
      float4 st; st.x = pan[i][0]; st.y = pan[i][1];
      st.z = pan[i][2]; st.w = pan[i][3];
      *(float4*)&foldp[(i * 128 + lt) * 4] = st;
    }
  }
  __syncthreads();
  if (grp == 0) {
#pragma unroll
    for (int i = 0; i < 4; ++i) {
      float4 h = *(const float4*)&foldp[(i * 128 + lt) * 4];
      // BLAS fold order: result = fadd(panLow, panHigh)
      pan[i][0] = __fadd_rn(pan[i][0], h.x);
      pan[i][1] = __fadd_rn(pan[i][1], h.y);
      pan[i][2] = __fadd_rn(pan[i][2], h.z);
      pan[i][3] = __fadd_rn(pan[i][3], h.w);
    }
  }
}

// ---- whole-K GEMM: K=512 (single panel, no fold), 256 thr, micro 4x2.
template<bool AFLOAT>
__device__ __forceinline__ void gemm_whole(
    const void* __restrict__ Abase, int Astride,  // elems
    const float* __restrict__ W,  // [o][512]
    int bBase, int oBase,
    float (&As)[2][2][32][32], float (&Ws)[2][2][32][68],
    float (&pan)[4][2])
{
  const int tid = threadIdx.x;
  const int ar = tid >> 3, ac4 = (tid & 7) << 2;  // A stage: 4 k-elems
  const int wr = tid >> 2, wk2 = (tid & 3) << 3;  // W stage: row wr, 8 k
  const int tb4 = (tid >> 5) << 2;                // compute: 4 b-rows
  const int to2 = (tid & 31) << 1;                // compute: 2 o-cols

  const float* Af = (const float*)Abase + (size_t)(bBase + ar) * Astride + ac4;
  const unsigned char* Ab = (const unsigned char*)Abase + (size_t)(bBase + ar) * Astride + ac4;
  const float* Wr = W + (size_t)(oBase + wr) * 512 + wk2;

  // prologue: tile 0
  {
    float4 w0 = *(const float4*)(Wr);
    float4 w1 = *(const float4*)(Wr + 4);
    if (AFLOAT) wrA4f(As[0][0], ac4, ar, *(const float4*)(Af));
    else        wrA4b(As[0][0], ac4, ar, *(const unsigned*)(Ab));
    wrW8(Ws[0][0], wk2, wr, w0, w1);
  }
  float4 paf; unsigned pab;
  if (AFLOAT) paf = *(const float4*)(Af + 32); else pab = *(const unsigned*)(Ab + 32);
  float4 pw0 = *(const float4*)(Wr + 32);
  float4 pw1 = *(const float4*)(Wr + 36);
  __syncthreads();

  int cb = 0;
#pragma unroll 1
  for (int kt = 0; kt < 16; ++kt) {
    float4 naf; unsigned nab; float4 nw0, nw1;
    if (kt + 2 < 16) {
      const int ko = (kt + 2) << 5;
      if (AFLOAT) naf = *(const float4*)(Af + ko); else nab = *(const unsigned*)(Ab + ko);
      nw0 = *(const float4*)(Wr + ko);
      nw1 = *(const float4*)(Wr + ko + 4);
    }
#pragma unroll
    for (int k = 0; k < 32; ++k) {
      const float4 a = *(const float4*)&As[0][cb][k][tb4];
      const float2 w = *(const float2*)&Ws[0][cb][k][to2];
      pan[0][0] = fmaf(a.x, w.x, pan[0][0]);
      pan[0][1] = fmaf(a.x, w.y, pan[0][1]);
      pan[1][0] = fmaf(a.y, w.x, pan[1][0]);
      pan[1][1] = fmaf(a.y, w.y, pan[1][1]);
      pan[2][0] = fmaf(a.z, w.x, pan[2][0]);
      pan[2][1] = fmaf(a.z, w.y, pan[2][1]);
      pan[3][0] = fmaf(a.w, w.x, pan[3][0]);
      pan[3][1] = fmaf(a.w, w.y, pan[3][1]);
    }
    if (kt + 1 < 16) {
      const int nb = cb ^ 1;
      if (AFLOAT) wrA4f(As[0][nb], ac4, ar, paf);
      else        wrA4b(As[0][nb], ac4, ar, pab);
      wrW8(Ws[0][nb], wk2, wr, pw0, pw1);
    }
    if (kt + 2 < 16) { paf = naf; pab = nab; pw0 = nw0; pw1 = nw1; }
    __syncthreads();
    cb ^= 1;
  }
}

// Blocks: g0 [0,64) g1 [64,128) g2 [128,192) g3 [192,256) g4 [256,288) g5 [288,296)
__global__ __launch_bounds__(256) void phase_kernel(
    const float* __restrict__ x,
    const float* __restrict__ W0, const float* __restrict__ W1,
    const float* __restrict__ W2a, const float* __restrict__ W2b,
    const float* __restrict__ W3, const float* __restrict__ W4,
    float* __restrict__ wf, float* __restrict__ out, int p)
{
  __shared__ float As[2][2][32][32];   // [grp][buf][k][b]  (16 KB)
  __shared__ float Ws[2][2][32][68];   // [grp][buf][k][o]  (34 KB)

  float* cnt = wf + OFF_CNT;
  float* c2a = wf + OFF_C2A;
  unsigned char* sb = (unsigned char*)(wf + OFF_BYTE);
  const int cur = p & 1, prev = cur ^ 1;

  const int blk = blockIdx.x;
  int g, lb, t;
  if (blk < 64)       { g = 0; lb = blk;       t = p;     }
  else if (blk < 128) { g = 1; lb = blk - 64;  t = p - 1; }
  else if (blk < 192) { g = 2; lb = blk - 128; t = p - 2; }
  else if (blk < 256) { g = 3; lb = blk - 192; t = p - 3; }
  else if (blk < 288) { g = 4; lb = blk - 256; t = p - 4; }
  else                { g = 5; lb = blk - 288; t = p - 5; }
  if (t < 0 || t >= NT) return;

  const int ntO = (g == 4) ? 8 : (g == 5) ? 2 : 16;
  const int N   = (g == 4) ? 512 : (g == 5) ? 128 : 1024;
  const int bBase = (lb / ntO) << 5;
  const int oBase = (lb % ntO) << 6;
  const int tid = threadIdx.x;

  if (g == 0 || g == 5) {
    // ---- whole-K stages ----
    float pan[4][2] = {{0.f,0.f},{0.f,0.f},{0.f,0.f},{0.f,0.f}};
    float alpha, vth; float* v;
    if (g == 0) {
      gemm_whole<true >(x + (size_t)t * 512, NT * 512, W0, bBase, oBase, As, Ws, pan);
      alpha = 0.90f; vth = 0.5f; v = wf + OFF_V0;
    } else {
      gemm_whole<false>(sb + BS3 + (size_t)prev * 65536, 512, W4, bBase, oBase, As, Ws, pan);
      alpha = 0.82f; vth = 0.8f; v = wf + OFF_VO;
    }
    const int tb4 = (tid >> 5) << 2;
    const int to2 = (tid & 31) << 1;
    unsigned char* sOut = sb + BS0 + (size_t)cur * 131072;  // g0 target (s0)
#pragma unroll
    for (int i = 0; i < 4; ++i) {
      const int b = bBase + tb4 + i;
      int si[2];
#pragma unroll
      for (int j = 0; j < 2; ++j) {
        const int o = oBase + to2 + j;
        float* vp = v + (size_t)b * N + o;
        float vv = __fadd_rn(__fmul_rn(alpha, *vp), pan[i][j]);
        int s = (vv >= vth) ? 1 : 0;
        float sf = (float)s;
        *vp = __fmul_rn(vv, __fsub_rn(1.0f, sf));
        si[j] = s;
        if (g == 5) {
          out[(size_t)b * (NT * 128) + (size_t)t * 128 + o] = sf;
          cnt[b * 128 + o] = __fadd_rn(cnt[b * 128 + o], sf);  // integer-exact
        }
      }
      if (g == 0) {
        *(unsigned short*)(sOut + (size_t)b * 1024 + oBase + to2) =
            (unsigned short)(si[0] | (si[1] << 8));
      }
    }
    return;
  }

  // ---- split K=1024 stages: g1 (L1), g2 (2a), g3 (2b), g4 (L3) ----
  const unsigned char* Ab; const float* Wm;
  switch (g) {
    case 1: Ab = sb + BS0 + (size_t)prev * 131072; Wm = W1;  break;  // s0
    case 2: Ab = sb + BS1 + (size_t)prev * 131072; Wm = W2a; break;  // s1
    case 3: Ab = sb + BS2 + (size_t)prev * 131072; Wm = W2b; break;  // s2
    default: Ab = sb + BS2 + (size_t)prev * 131072; Wm = W3; break;  // s2 (L3)
  }
  const int Astride = 1024;

  float pan[4][4];
#pragma unroll
  for (int i = 0; i < 4; ++i)
#pragma unroll
    for (int j = 0; j < 4; ++j) pan[i][j] = 0.f;

  gemm_split(Ab, Astride, Wm, bBase, oBase, As, Ws, pan);

  if (tid >= 128) return;  // only group 0 holds the folded result (no more barriers)
  const int lt = tid;
  const int tb4 = (lt >> 4) << 2;
  const int to4 = (lt & 15) << 2;

  if (g == 2) {
    // stage 2a: store folded GEMM result for next phase's 2b combine
    float* dst = c2a + (size_t)cur * 131072;
#pragma unroll
    for (int i = 0; i < 4; ++i) {
      const int b = bBase + tb4 + i;
      float4 st; st.x = pan[i][0]; st.y = pan[i][1];
      st.z = pan[i][2]; st.w = pan[i][3];
      *(float4*)(dst + (size_t)b * 1024 + oBase + to4) = st;
    }
    return;
  }

  float alpha; float* v; unsigned char* sOut;
  switch (g) {
    case 1: alpha = 0.95f; v = wf + OFF_V1; sOut = sb + BS1 + (size_t)cur * 131072; break;
    case 3: alpha = 0.93f; v = wf + OFF_V2; sOut = sb + BS2 + (size_t)cur * 131072; break;
    default: alpha = 0.90f; v = wf + OFF_V3; sOut = sb + BS3 + (size_t)cur * 65536; break;
  }
  const float* c2aPrev = c2a + (size_t)prev * 131072;

#pragma unroll
  for (int i = 0; i < 4; ++i) {
    const int b = bBase + tb4 + i;
    float cin[4];
    if (g == 3) {
      float4 ca = *(const float4*)(c2aPrev + (size_t)b * 1024 + oBase + to4);
      // reference: ONE __fadd_rn combining the two matmuls, W2a result first
      cin[0] = __fadd_rn(ca.x, pan[i][0]);
      cin[1] = __fadd_rn(ca.y, pan[i][1]);
      cin[2] = __fadd_rn(ca.z, pan[i][2]);
      cin[3] = __fadd_rn(ca.w, pan[i][3]);
    } else {
      cin[0] = pan[i][0]; cin[1] = pan[i][1];
      cin[2] = pan[i][2]; cin[3] = pan[i][3];
    }
    unsigned packed = 0;
#pragma unroll
    for (int j = 0; j < 4; ++j) {
      const int o = oBase + to4 + j;
      float* vp = v + (size_t)b * N + o;
      // numpy: mul rounded, then add rounded — NO fma
      float vv = __fadd_rn(__fmul_rn(alpha, *vp), cin[j]);
      int s = (vv >= 0.5f) ? 1 : 0;
      float sf = (float)s;
      *vp = __fmul_rn(vv, __fsub_rn(1.0f, sf));
      packed |= (unsigned)s << (8 * j);
    }
    *(unsigned*)(sOut + (size_t)b * N + oBase + to4) = packed;
  }
}

__global__ __launch_bounds__(256) void fin_kernel(const float* __restrict__ counts,
                                                  float* __restrict__ out) {
  int i = blockIdx.x * blockDim.x + threadIdx.x;
  if (i < 128 * 128) out[(size_t)128 * NT * 128 + i] = counts[i];
}

extern "C" void kernel_launch(void* const* d_in, const int* in_sizes, int n_in,
                              void* d_out, int out_size, void* d_ws, size_t ws_size,
                              hipStream_t stream) {
  const float* x   = (const float*)d_in[0];
  const float* W0  = (const float*)d_in[1];
  const float* W1  = (const float*)d_in[2];
  const float* W2a = (const float*)d_in[3];
  const float* W2b = (const float*)d_in[4];
  const float* W3  = (const float*)d_in[5];
  const float* W4  = (const float*)d_in[6];
  float* wf  = (float*)d_ws;
  float* out = (float*)d_out;

  init_kernel<<<512, 256, 0, stream>>>(wf);
  for (int p = 0; p < NT + 5; ++p) {
    phase_kernel<<<296, 256, 0, stream>>>(x, W0, W1, W2a, W2b, W3, W4, wf, out, p);
  }
  fin_kernel<<<64, 256, 0, stream>>>(wf + OFF_CNT, out);
}